// Round 5
// baseline (315.341 us; speedup 1.0000x reference)
//
#include <hip/hip_runtime.h>
#include <hip/hip_bf16.h>
#include <math.h>

#define BB 4
#define NN 3000
#define FF 128
#define NKC 94          // number of 32-wide K chunks (94*32 = 3008 >= 3000)
#define NIT 188         // number of 16-row tiles (188*16 = 3008)

typedef __bf16 bf16x8 __attribute__((ext_vector_type(8)));
typedef float  f32x4  __attribute__((ext_vector_type(4)));

// ---------------- K1: fused degree + A-pack, barrier-free -----------------------
// One wave per (16-row tile, k-half). Source lane s loads row s>>2, col-block
// s&3 (8 cols, two float4). Transpose to MFMA A-fragment order is a pure lane
// permutation of the 16-B payload: target lane l=(m=l&15, quad=l>>4) takes
// source lane m*4+quad -> 4x ds_bpermute. No LDS tiles, no __syncthreads.
// Row sums go to deg[] via 2 atomicAdds/row (deg pre-zeroed by memset).
__global__ __launch_bounds__(256) void k_degpack(const float* __restrict__ adj,
                                                 __bf16* __restrict__ apk,
                                                 float* __restrict__ deg) {
    const int b    = blockIdx.y;
    const int gw   = blockIdx.x * 4 + (threadIdx.x >> 6);   // 0..375
    const int it   = gw >> 1;
    const int half = gw & 1;
    const int l    = threadIdx.x & 63;
    const int srow = l >> 2, scb = l & 3;
    const int m    = l & 15, quad = l >> 4;
    const int i0   = it * 16;
    const int irow = i0 + srow;
    const bool rowok = irow < NN;
    const float* rp = adj + ((size_t)b * NN + (rowok ? irow : 0)) * NN;
    __bf16* dst = apk + ((size_t)(b * NIT + it) * NKC) * 512 + l * 8;
    const int addr = (m * 4 + quad) * 4;    // source lane * 4 for bpermute
    float rs = 0.f;
    const int kc0 = half * 47, kc1 = kc0 + 47;
    #pragma unroll 4
    for (int kc = kc0; kc < kc1; ++kc) {
        int col = kc * 32 + scb * 8;
        float4 u = {0.f, 0.f, 0.f, 0.f}, v = {0.f, 0.f, 0.f, 0.f};
        if (rowok && col < NN) {            // NN%8==0: 8-col block all-in/all-out
            u = *(const float4*)(rp + col);
            v = *(const float4*)(rp + col + 4);
        }
        rs += ((u.x + u.y) + (u.z + u.w)) + ((v.x + v.y) + (v.z + v.w));
        union { __bf16 h[8]; int d[4]; } P;
        P.h[0] = (__bf16)u.x; P.h[1] = (__bf16)u.y;
        P.h[2] = (__bf16)u.z; P.h[3] = (__bf16)u.w;
        P.h[4] = (__bf16)v.x; P.h[5] = (__bf16)v.y;
        P.h[6] = (__bf16)v.z; P.h[7] = (__bf16)v.w;
        union { int d[4]; bf16x8 f; } Q;
        #pragma unroll
        for (int t2 = 0; t2 < 4; ++t2)
            Q.d[t2] = __builtin_amdgcn_ds_bpermute(addr, P.d[t2]);
        *(bf16x8*)(dst + (size_t)kc * 512) = Q.f;
    }
    // lanes {r*4 .. r*4+3} hold partials of row r
    rs += __shfl_down(rs, 2, 64);
    rs += __shfl_down(rs, 1, 64);
    if ((l & 3) == 0 && rowok) atomicAdd(&deg[b * NN + irow], rs);
}

// ---------------- K2: pack xs = rsqrt(deg_k+1) * x[k][f] into B-fragment order --
// xpk[b][nt][kc][lane][8], lane = (f%16) + 16*quad, k = kc*32 + quad*8 + j.
__global__ __launch_bounds__(256) void k_xpk(const float* __restrict__ x,
                                             const float* __restrict__ deg,
                                             __bf16* __restrict__ xpk) {
    int b  = blockIdx.y, kc = blockIdx.x;
    int t  = threadIdx.x, w = t >> 6, l = t & 63;
    int m  = l & 15, q = l >> 4;
    #pragma unroll
    for (int h = 0; h < 2; ++h) {
        int nt = w + h * 4;
        int f  = nt * 16 + m;
        bf16x8 v;
        #pragma unroll
        for (int j = 0; j < 8; ++j) {
            int k = kc * 32 + q * 8 + j;
            float val = 0.f;
            if (k < NN) {
                float di = 1.0f / sqrtf(deg[b * NN + k] + 1.0f);
                val = di * x[((size_t)b * NN + k) * FF + f];
            }
            v[j] = (__bf16)val;
        }
        *(bf16x8*)(xpk + ((size_t)(b * 8 + nt) * NKC + kc) * 512 + l * 8) = v;
    }
}

// ---------------- K2b: pack theta into MFMA B-fragment order --------------------
__global__ __launch_bounds__(256) void k_thpk(const float* __restrict__ theta,
                                              __bf16* __restrict__ thpk) {
    int kc = blockIdx.x;
    int t  = threadIdx.x, w = t >> 6, l = t & 63;
    int m  = l & 15, q = l >> 4;
    #pragma unroll
    for (int h = 0; h < 2; ++h) {
        int nt = w + h * 4;
        bf16x8 v;
        #pragma unroll
        for (int j = 0; j < 8; ++j) {
            int k = kc * 32 + q * 8 + j;
            v[j] = (__bf16)theta[k * FF + nt * 16 + m];
        }
        *(bf16x8*)(thpk + ((size_t)(nt * 4 + kc)) * 512 + l * 8) = v;
    }
}

// ---------------- K3 (fused): out = beta*(support@theta) + (1-beta)*support ------
// support = (1-alpha)*hi + alpha*h0,  hi_i = dis_i*(adj_i . xs) + dis_i^2 * x_i
// Main loop: pure fragment streaming (A from apk, B from xpk), no LDS, no barriers.
__global__ __launch_bounds__(256) void k_agg(const __bf16* __restrict__ apk,
                                             const __bf16* __restrict__ xpk,
                                             const __bf16* __restrict__ thpk,
                                             const float* __restrict__ x,
                                             const float* __restrict__ h0,
                                             const float* __restrict__ deg,
                                             float* __restrict__ out,
                                             const float* __restrict__ alpha_p,
                                             const float* __restrict__ lamda_p,
                                             const int* __restrict__ l_p) {
    __shared__ __bf16 stile[16][136];
    const int b  = blockIdx.y;
    const int it = blockIdx.x;
    const int i0 = it * 16;
    const int t  = threadIdx.x, w = t >> 6, l = t & 63;
    const int m  = l & 15, quad = l >> 4;
    const int n0 = w * 32;
    const __bf16* Ap = apk + ((size_t)(b * NIT + it) * NKC) * 512 + l * 8;
    const __bf16* B0 = xpk + ((size_t)(b * 8 + 2 * w) * NKC) * 512 + l * 8;
    const __bf16* B1 = B0 + (size_t)NKC * 512;
    f32x4 acc0 = {0.f, 0.f, 0.f, 0.f};
    f32x4 acc1 = {0.f, 0.f, 0.f, 0.f};
    #pragma unroll 4
    for (int kc = 0; kc < NKC; ++kc) {
        bf16x8 a  = *(const bf16x8*)(Ap + (size_t)kc * 512);
        bf16x8 b0 = *(const bf16x8*)(B0 + (size_t)kc * 512);
        bf16x8 b1 = *(const bf16x8*)(B1 + (size_t)kc * 512);
        acc0 = __builtin_amdgcn_mfma_f32_16x16x32_bf16(a, b0, acc0, 0, 0, 0);
        acc1 = __builtin_amdgcn_mfma_f32_16x16x32_bf16(a, b1, acc1, 0, 0, 0);
    }
    // ---- epilogue: support values; stage tile in A-layout (bf16) ----
    const float alpha = *alpha_p;
    const float beta  = logf(*lamda_p / (float)(*l_p) + 1.0f);
    float s0v[4], s1v[4];
    #pragma unroll
    for (int r = 0; r < 4; ++r) {
        int row  = quad * 4 + r;
        int irow = i0 + row;
        float s0 = 0.f, s1 = 0.f;
        if (irow < NN) {
            float  di   = 1.0f / sqrtf(deg[b * NN + irow] + 1.0f);
            size_t base = ((size_t)b * NN + irow) * FF;
            int c0 = n0 + m, c1 = n0 + 16 + m;
            s0 = (1.f - alpha) * (di * acc0[r] + di * di * x[base + c0]) + alpha * h0[base + c0];
            s1 = (1.f - alpha) * (di * acc1[r] + di * di * x[base + c1]) + alpha * h0[base + c1];
        }
        s0v[r] = s0; s1v[r] = s1;
        stile[row][n0 + m]      = (__bf16)s0;
        stile[row][n0 + 16 + m] = (__bf16)s1;
    }
    __syncthreads();
    // ---- theta matmul on the 16x128 support tile ----
    f32x4 o0 = {0.f, 0.f, 0.f, 0.f};
    f32x4 o1 = {0.f, 0.f, 0.f, 0.f};
    const __bf16* T0 = thpk + (size_t)(2 * w * 4) * 512 + l * 8;
    const __bf16* T1 = T0 + 4 * 512;
    #pragma unroll
    for (int kc = 0; kc < 4; ++kc) {
        bf16x8 a   = *(const bf16x8*)&stile[m][kc * 32 + quad * 8];
        bf16x8 tb0 = *(const bf16x8*)(T0 + (size_t)kc * 512);
        bf16x8 tb1 = *(const bf16x8*)(T1 + (size_t)kc * 512);
        o0 = __builtin_amdgcn_mfma_f32_16x16x32_bf16(a, tb0, o0, 0, 0, 0);
        o1 = __builtin_amdgcn_mfma_f32_16x16x32_bf16(a, tb1, o1, 0, 0, 0);
    }
    const float omb = 1.f - beta;
    #pragma unroll
    for (int r = 0; r < 4; ++r) {
        int irow = i0 + quad * 4 + r;
        if (irow < NN) {
            size_t base = ((size_t)b * NN + irow) * FF;
            out[base + n0 + m]      = beta * o0[r] + omb * s0v[r];
            out[base + n0 + 16 + m] = beta * o1[r] + omb * s1v[r];
        }
    }
}

extern "C" void kernel_launch(void* const* d_in, const int* in_sizes, int n_in,
                              void* d_out, int out_size, void* d_ws, size_t ws_size,
                              hipStream_t stream) {
    const float* x      = (const float*)d_in[0];
    const float* adj    = (const float*)d_in[1];
    const float* h0     = (const float*)d_in[2];
    const float* theta  = (const float*)d_in[3];
    const float* lamda  = (const float*)d_in[4];
    const float* alpha  = (const float*)d_in[5];
    const int*   l      = (const int*)d_in[6];
    float* out = (float*)d_out;

    char*   ws   = (char*)d_ws;
    float*  deg  = (float*)ws;                         // 48,000 B (zeroed below)
    __bf16* xpk  = (__bf16*)(ws + 65536);              // 3,080,192 B
    __bf16* thpk = (__bf16*)(ws + 3200000);            // 32,768 B
    __bf16* apk  = (__bf16*)(ws + 4 * 1024 * 1024);    // 72,384,512 B

    hipMemsetAsync(deg, 0, BB * NN * sizeof(float), stream);
    k_degpack<<<dim3(94, BB), 256, 0, stream>>>(adj, apk, deg);
    k_thpk<<<dim3(4), 256, 0, stream>>>(theta, thpk);
    k_xpk<<<dim3(NKC, BB), 256, 0, stream>>>(x, deg, xpk);
    k_agg<<<dim3(NIT, BB), 256, 0, stream>>>(apk, xpk, thpk, x, h0, deg, out,
                                             alpha, lamda, l);
}

// Round 6
// 277.146 us; speedup vs baseline: 1.1378x; 1.1378x over previous
//
#include <hip/hip_runtime.h>
#include <hip/hip_bf16.h>
#include <math.h>

#define BB 4
#define NN 3000
#define FF 128
#define NKC 96          // 32-wide K chunks padded: 6 big chunks x 16 (96*32 = 3072)
#define NIT 188         // 16-row tiles (188*16 = 3008)

typedef __bf16 bf16x8 __attribute__((ext_vector_type(8)));
typedef float  f32x4  __attribute__((ext_vector_type(4)));

// ---------------- K1: dis[b*NN+i] = 1/sqrt(1 + sum_j adj[b,i,j]) ----------------
// one wave per row; coalesced float4 row reads. Pure-BW (~25 us).
__global__ __launch_bounds__(256) void k_deg(const float* __restrict__ adj,
                                             float* __restrict__ dis) {
    int wid  = (blockIdx.x * 256 + threadIdx.x) >> 6;
    int lane = threadIdx.x & 63;
    if (wid >= BB * NN) return;
    const float4* row = (const float4*)(adj + (size_t)wid * NN);
    float s = 0.f;
    for (int c = lane; c < NN / 4; c += 64) {
        float4 v = row[c];
        s += (v.x + v.y) + (v.z + v.w);
    }
    for (int off = 32; off > 0; off >>= 1) s += __shfl_down(s, off, 64);
    if (lane == 0) dis[wid] = 1.0f / sqrtf(s + 1.0f);
}

// ---------------- K2: pack xs = dis_k * x[k][f] into MFMA B-fragment order ------
// xpk[b][nt][kc][lane][8], lane = (f%16) + 16*quad, k = kc*32 + quad*8 + j.
__global__ __launch_bounds__(256) void k_xpk(const float* __restrict__ x,
                                             const float* __restrict__ dis,
                                             __bf16* __restrict__ xpk) {
    int b  = blockIdx.y, kc = blockIdx.x;
    int t  = threadIdx.x, w = t >> 6, l = t & 63;
    int m  = l & 15, q = l >> 4;
    #pragma unroll
    for (int h = 0; h < 2; ++h) {
        int nt = w + h * 4;
        int f  = nt * 16 + m;
        bf16x8 v;
        #pragma unroll
        for (int j = 0; j < 8; ++j) {
            int k = kc * 32 + q * 8 + j;
            float val = 0.f;
            if (k < NN) val = dis[b * NN + k] * x[((size_t)b * NN + k) * FF + f];
            v[j] = (__bf16)val;
        }
        *(bf16x8*)(xpk + ((size_t)(b * 8 + nt) * NKC + kc) * 512 + l * 8) = v;
    }
}

// ---------------- K2b: pack theta into MFMA B-fragment order --------------------
__global__ __launch_bounds__(256) void k_thpk(const float* __restrict__ theta,
                                              __bf16* __restrict__ thpk) {
    int kc = blockIdx.x;
    int t  = threadIdx.x, w = t >> 6, l = t & 63;
    int m  = l & 15, q = l >> 4;
    #pragma unroll
    for (int h = 0; h < 2; ++h) {
        int nt = w + h * 4;
        bf16x8 v;
        #pragma unroll
        for (int j = 0; j < 8; ++j) {
            int k = kc * 32 + q * 8 + j;
            v[j] = (__bf16)theta[k * FF + nt * 16 + m];
        }
        *(bf16x8*)(thpk + ((size_t)(nt * 4 + kc)) * 512 + l * 8) = v;
    }
}

// ---------------- K3 (fused): out = beta*(support@theta) + (1-beta)*support ------
// support = (1-alpha)*hi + alpha*h0,  hi_i = dis_i*(adj_i . xs) + dis_i^2 * x_i
// Double-buffered BK=512 adj staging, ONE barrier per chunk; prefetch chunk c+1
// before computing chunk c so the vmcnt drain before the barrier overlaps MFMA.
__global__ __launch_bounds__(256) void k_agg(const float* __restrict__ adj,
                                             const __bf16* __restrict__ xpk,
                                             const __bf16* __restrict__ thpk,
                                             const float* __restrict__ x,
                                             const float* __restrict__ h0,
                                             const float* __restrict__ dis,
                                             float* __restrict__ out,
                                             const float* __restrict__ alpha_p,
                                             const float* __restrict__ lamda_p,
                                             const int* __restrict__ l_p) {
    __shared__ __bf16 tile[2][16][520];   // 512 cols + 8 pad, bf16
    __shared__ __bf16 stile[16][136];
    const int b  = blockIdx.y;
    const int it = blockIdx.x;
    const int i0 = it * 16;
    const int t  = threadIdx.x, w = t >> 6, l = t & 63;
    const int m  = l & 15, quad = l >> 4;
    const int n0 = w * 32;
    const __bf16* B0 = xpk + ((size_t)(b * 8 + 2 * w) * NKC) * 512 + l * 8;
    const __bf16* B1 = B0 + (size_t)NKC * 512;
    f32x4 acc0 = {0.f, 0.f, 0.f, 0.f};
    f32x4 acc1 = {0.f, 0.f, 0.f, 0.f};

    float4 pu[4], pv[4];
    // wave w stages rows {w, 4+w, 8+w, 12+w}; lane l covers cols [l*8, l*8+8)
    auto load_chunk = [&](int c) {
        int k0 = c * 512;
        #pragma unroll
        for (int i = 0; i < 4; ++i) {
            int row  = i * 4 + w;
            int irow = i0 + row;
            int col  = k0 + l * 8;
            float4 u = {0.f, 0.f, 0.f, 0.f}, v = {0.f, 0.f, 0.f, 0.f};
            if (irow < NN && col < NN) {   // NN%8==0: 8-col block all-in/all-out
                const float* p = adj + ((size_t)b * NN + irow) * NN + col;
                u = *(const float4*)p;
                v = *(const float4*)(p + 4);
            }
            pu[i] = u; pv[i] = v;
        }
    };
    auto store_chunk = [&](int cb) {
        #pragma unroll
        for (int i = 0; i < 4; ++i) {
            int row = i * 4 + w;
            bf16x8 s;
            s[0] = (__bf16)pu[i].x; s[1] = (__bf16)pu[i].y;
            s[2] = (__bf16)pu[i].z; s[3] = (__bf16)pu[i].w;
            s[4] = (__bf16)pv[i].x; s[5] = (__bf16)pv[i].y;
            s[6] = (__bf16)pv[i].z; s[7] = (__bf16)pv[i].w;
            *(bf16x8*)&tile[cb][row][l * 8] = s;
        }
    };

    load_chunk(0);
    store_chunk(0);
    __syncthreads();
    for (int c = 0; c < 6; ++c) {
        int cb = c & 1;
        if (c < 5) load_chunk(c + 1);
        #pragma unroll 4
        for (int kcl = 0; kcl < 16; ++kcl) {
            int kc = c * 16 + kcl;
            bf16x8 a  = *(const bf16x8*)&tile[cb][m][kcl * 32 + quad * 8];
            bf16x8 b0 = *(const bf16x8*)(B0 + (size_t)kc * 512);
            bf16x8 b1 = *(const bf16x8*)(B1 + (size_t)kc * 512);
            acc0 = __builtin_amdgcn_mfma_f32_16x16x32_bf16(a, b0, acc0, 0, 0, 0);
            acc1 = __builtin_amdgcn_mfma_f32_16x16x32_bf16(a, b1, acc1, 0, 0, 0);
        }
        if (c < 5) store_chunk(cb ^ 1);
        __syncthreads();
    }

    // ---- epilogue: support values; stage tile in A-layout (bf16) ----
    const float alpha = *alpha_p;
    const float beta  = logf(*lamda_p / (float)(*l_p) + 1.0f);
    float s0v[4], s1v[4];
    #pragma unroll
    for (int r = 0; r < 4; ++r) {
        int row  = quad * 4 + r;
        int irow = i0 + row;
        float s0 = 0.f, s1 = 0.f;
        if (irow < NN) {
            float  di   = dis[b * NN + irow];
            size_t base = ((size_t)b * NN + irow) * FF;
            int c0 = n0 + m, c1 = n0 + 16 + m;
            s0 = (1.f - alpha) * (di * acc0[r] + di * di * x[base + c0]) + alpha * h0[base + c0];
            s1 = (1.f - alpha) * (di * acc1[r] + di * di * x[base + c1]) + alpha * h0[base + c1];
        }
        s0v[r] = s0; s1v[r] = s1;
        stile[row][n0 + m]      = (__bf16)s0;
        stile[row][n0 + 16 + m] = (__bf16)s1;
    }
    __syncthreads();
    // ---- theta matmul on the 16x128 support tile ----
    f32x4 o0 = {0.f, 0.f, 0.f, 0.f};
    f32x4 o1 = {0.f, 0.f, 0.f, 0.f};
    const __bf16* T0 = thpk + (size_t)(2 * w * 4) * 512 + l * 8;
    const __bf16* T1 = T0 + 4 * 512;
    #pragma unroll
    for (int kc = 0; kc < 4; ++kc) {
        bf16x8 a   = *(const bf16x8*)&stile[m][kc * 32 + quad * 8];
        bf16x8 tb0 = *(const bf16x8*)(T0 + (size_t)kc * 512);
        bf16x8 tb1 = *(const bf16x8*)(T1 + (size_t)kc * 512);
        o0 = __builtin_amdgcn_mfma_f32_16x16x32_bf16(a, tb0, o0, 0, 0, 0);
        o1 = __builtin_amdgcn_mfma_f32_16x16x32_bf16(a, tb1, o1, 0, 0, 0);
    }
    const float omb = 1.f - beta;
    #pragma unroll
    for (int r = 0; r < 4; ++r) {
        int irow = i0 + quad * 4 + r;
        if (irow < NN) {
            size_t base = ((size_t)b * NN + irow) * FF;
            out[base + n0 + m]      = beta * o0[r] + omb * s0v[r];
            out[base + n0 + 16 + m] = beta * o1[r] + omb * s1v[r];
        }
    }
}

extern "C" void kernel_launch(void* const* d_in, const int* in_sizes, int n_in,
                              void* d_out, int out_size, void* d_ws, size_t ws_size,
                              hipStream_t stream) {
    const float* x      = (const float*)d_in[0];
    const float* adj    = (const float*)d_in[1];
    const float* h0     = (const float*)d_in[2];
    const float* theta  = (const float*)d_in[3];
    const float* lamda  = (const float*)d_in[4];
    const float* alpha  = (const float*)d_in[5];
    const int*   l      = (const int*)d_in[6];
    float* out = (float*)d_out;

    char*   ws   = (char*)d_ws;
    float*  dis  = (float*)ws;                 // 48,000 B
    __bf16* xpk  = (__bf16*)(ws + 65536);      // 4*8*96*512*2 = 3,145,728 B
    __bf16* thpk = (__bf16*)(ws + 3276800);    // 32,768 B

    k_deg<<<dim3((BB * NN) / 4), 256, 0, stream>>>(adj, dis);
    k_thpk<<<dim3(4), 256, 0, stream>>>(theta, thpk);
    k_xpk<<<dim3(NKC, BB), 256, 0, stream>>>(x, dis, xpk);
    k_agg<<<dim3(NIT, BB), 256, 0, stream>>>(adj, xpk, thpk, x, h0, dis, out,
                                             alpha, lamda, l);
}